// Round 4
// baseline (782.699 us; speedup 1.0000x reference)
//
#include <hip/hip_runtime.h>
#include <hip/hip_cooperative_groups.h>

namespace cg = cooperative_groups;

typedef float f32x4 __attribute__((ext_vector_type(4)));

#define B 256
#define D 256
#define N 200000
#define C 1000
#define NBLK 1024
#define NTHR 256
#define CM_CHUNKS 8
#define ROWS_C 20000   // rows copied during the scan-overlap phase (even)

// ---------------- ws layout (bytes) ----------------
#define WS_NEWROWS_OFF  0          // B*D f32 = 262144
#define WS_OVERRIDE_OFF 262144     // N int   = 800000
#define WS_HIST_OFF     1062144    // C int
#define WS_OFFS_OFF     1066144    // C int
#define WS_FILLPOS_OFF  1070144    // C int
#define WS_TOUCHED_OFF  1074144    // C int
#define WS_SUMS_OFF     1078144    // C*D f32 = 1024000
#define WS_ROWLIST_OFF  2102144    // N int   -> total 2,902,144

__device__ __forceinline__ void copy_row2(int row0, int lane,
        const f32x4* __restrict__ feats4, const f32x4* __restrict__ new4,
        const int* __restrict__ override_, f32x4* __restrict__ out4) {
    // copies rows row0 and row0+1 (caller guarantees row0+1 < N)
    int ov0 = override_[row0];
    int ov1 = override_[row0 + 1];
    const f32x4* s0 = (ov0 >= 0) ? (new4 + (size_t)ov0 * 64) : (feats4 + (size_t)row0 * 64);
    const f32x4* s1 = (ov1 >= 0) ? (new4 + (size_t)ov1 * 64) : (feats4 + (size_t)(row0 + 1) * 64);
    f32x4 v0 = __builtin_nontemporal_load(s0 + lane);
    f32x4 v1 = __builtin_nontemporal_load(s1 + lane);
    out4[(size_t)row0 * 64 + lane] = v0;
    out4[(size_t)(row0 + 1) * 64 + lane] = v1;
}

__global__ __launch_bounds__(NTHR, 4) void mega_kernel(
    const float* __restrict__ inputs, const float* __restrict__ features,
    const float* __restrict__ cluster_mean, const int* __restrict__ indexes,
    const int* __restrict__ labels, const int* __restrict__ targets,
    float* __restrict__ out_logits, float* __restrict__ out_feats,
    float* __restrict__ out_cm,
    float* __restrict__ new_rows, int* __restrict__ override_,
    int* __restrict__ hist, int* __restrict__ offs, int* __restrict__ fillpos,
    int* __restrict__ touched, float* __restrict__ sums, int* __restrict__ rowlist)
{
    cg::grid_group grid = cg::this_grid();
    const int t    = threadIdx.x;
    const int blk  = blockIdx.x;
    const int gtid = blk * NTHR + t;
    const int wave = t >> 6;
    const int lane = t & 63;

    __shared__ float sbuf[256];   // logits input row
    __shared__ int   sidx[256];   // prep
    __shared__ int   swt[4];      // scan warp totals
    __shared__ float wpart[4];    // new_rows partial sums
    __shared__ float stot;        // new_rows total

    const f32x4* feats4 = (const f32x4*)features;
    const f32x4* new4   = (const f32x4*)new_rows;
    f32x4*       out4   = (f32x4*)out_feats;

    // ---------------- Phase A: logits (blocks 0..255) || ws init (256..1023) ----
    if (blk < 256) {
        int b = blk;
        sbuf[t] = inputs[b * D + t];
        __syncthreads();
        const f32x4* cmv = (const f32x4*)cluster_mean;
        for (int c = t; c < C; c += NTHR) {
            const f32x4* cm = cmv + (size_t)c * 64;
            float a0 = 0.f, a1 = 0.f, a2 = 0.f, a3 = 0.f;
            #pragma unroll 8
            for (int d4 = 0; d4 < 64; ++d4) {
                f32x4 v = cm[d4];
                const float* si = sbuf + d4 * 4;
                a0 += v.x * si[0];
                a1 += v.y * si[1];
                a2 += v.z * si[2];
                a3 += v.w * si[3];
            }
            out_logits[(size_t)b * C + c] = (a0 + a1) + (a2 + a3);
        }
    } else {
        const int total = N + C + C + C * D;
        const int stride = (NBLK - 256) * NTHR;
        for (int i = (blk - 256) * NTHR + t; i < total; i += stride) {
            if (i < N)              override_[i] = -1;
            else if (i < N + C)     hist[i - N] = 0;
            else if (i < N + 2 * C) touched[i - N - C] = 0;
            else                    sums[i - N - 2 * C] = 0.0f;
        }
    }
    grid.sync();

    // ---------------- Phase B: prep (blk 0) || new_rows (1..256) || hist (257..1023)
    if (blk == 0) {
        sidx[t] = indexes[t];
        __syncthreads();
        bool win = true;
        for (int j = t + 1; j < B; ++j) {
            if (sidx[j] == sidx[t]) { win = false; break; }
        }
        if (win) override_[sidx[t]] = t;   // last write wins
        touched[targets[t]] = 1;
    } else if (blk <= 256) {
        int b = blk - 1;
        int r = indexes[b];
        float x = 0.5f * features[(size_t)r * D + t] + 0.5f * inputs[b * D + t];
        float s = x * x;
        #pragma unroll
        for (int off = 32; off > 0; off >>= 1) s += __shfl_down(s, off);
        if ((t & 63) == 0) wpart[t >> 6] = s;
        __syncthreads();
        if (t == 0) stot = (wpart[0] + wpart[1]) + (wpart[2] + wpart[3]);
        __syncthreads();
        new_rows[b * D + t] = x / sqrtf(stot + 1e-12f);
    } else {
        const int stride = (NBLK - 257) * NTHR;
        for (int i = (blk - 257) * NTHR + t; i < N; i += stride)
            atomicAdd(&hist[labels[i]], 1);
    }
    grid.sync();

    // ---------------- Phase C: scan (blk 0) || feats copy rows [0, ROWS_C) ------
    if (blk == 0) {
        int base = t * 4;
        int h0 = (base + 0 < C) ? hist[base + 0] : 0;
        int h1 = (base + 1 < C) ? hist[base + 1] : 0;
        int h2 = (base + 2 < C) ? hist[base + 2] : 0;
        int h3 = (base + 3 < C) ? hist[base + 3] : 0;
        int tot = h0 + h1 + h2 + h3;
        int scan = tot;
        #pragma unroll
        for (int off = 1; off < 64; off <<= 1) {
            int v = __shfl_up(scan, off);
            if (lane >= off) scan += v;
        }
        if (lane == 63) swt[t >> 6] = scan;
        __syncthreads();
        int wbase = 0;
        for (int i = 0; i < (t >> 6); ++i) wbase += swt[i];
        int excl = wbase + scan - tot;
        if (base + 0 < C) { offs[base + 0] = excl;                fillpos[base + 0] = excl; }
        if (base + 1 < C) { offs[base + 1] = excl + h0;           fillpos[base + 1] = excl + h0; }
        if (base + 2 < C) { offs[base + 2] = excl + h0 + h1;      fillpos[base + 2] = excl + h0 + h1; }
        if (base + 3 < C) { offs[base + 3] = excl + h0 + h1 + h2; fillpos[base + 3] = excl + h0 + h1 + h2; }
    } else {
        const int totw = (NBLK - 1) * 4;
        int gw = (blk - 1) * 4 + wave;
        for (int r = 2 * gw; r < ROWS_C; r += 2 * totw)
            copy_row2(r, lane, feats4, new4, override_, out4);
    }
    grid.sync();

    // ---------------- Phase D: fill rowlist || feats copy rows [ROWS_C, N) ------
    for (int i = gtid; i < N; i += NBLK * NTHR) {
        int lab = labels[i];
        if (touched[lab]) {
            int p = atomicAdd(&fillpos[lab], 1);
            rowlist[p] = i;
        }
    }
    {
        const int totw = NBLK * 4;
        int gw = blk * 4 + wave;
        for (int r = ROWS_C + 2 * gw; r < N; r += 2 * totw)
            copy_row2(r, lane, feats4, new4, override_, out4);
    }
    grid.sync();

    // ---------------- Phase E: cluster sums from out_feats (L3-hot) -------------
    for (int u = blk; u < C * CM_CHUNKS; u += NBLK) {
        int c = u >> 3;          // CM_CHUNKS == 8
        int k = u & 7;
        if (!touched[c]) continue;
        int cnt = hist[c];
        if (k >= cnt) continue;
        int off = offs[c];
        float acc = 0.0f;
        for (int j = k; j < cnt; j += CM_CHUNKS)
            acc += out_feats[(size_t)rowlist[off + j] * D + t];
        atomicAdd(&sums[(size_t)c * D + t], acc);
    }
    grid.sync();

    // ---------------- Phase F: means --------------------------------------------
    for (int c = blk; c < C; c += NBLK) {
        float out;
        if (touched[c]) out = sums[(size_t)c * D + t] / fmaxf((float)hist[c], 1.0f);
        else            out = cluster_mean[(size_t)c * D + t];
        out_cm[(size_t)c * D + t] = out;
    }
}

extern "C" void kernel_launch(void* const* d_in, const int* in_sizes, int n_in,
                              void* d_out, int out_size, void* d_ws, size_t ws_size,
                              hipStream_t stream) {
    const float* inputs       = (const float*)d_in[0];
    const float* features     = (const float*)d_in[1];
    const float* cluster_mean = (const float*)d_in[2];
    const int*   indexes      = (const int*)d_in[3];
    const int*   labels       = (const int*)d_in[4];
    const int*   targets      = (const int*)d_in[5];

    float* out_logits = (float*)d_out;                      // B*C
    float* out_feats  = out_logits + (size_t)B * C;         // N*D
    float* out_cm     = out_feats + (size_t)N * D;          // C*D

    char* ws = (char*)d_ws;
    float* new_rows = (float*)(ws + WS_NEWROWS_OFF);
    int*   override_= (int*)(ws + WS_OVERRIDE_OFF);
    int*   hist     = (int*)(ws + WS_HIST_OFF);
    int*   offs     = (int*)(ws + WS_OFFS_OFF);
    int*   fillpos  = (int*)(ws + WS_FILLPOS_OFF);
    int*   touched  = (int*)(ws + WS_TOUCHED_OFF);
    float* sums     = (float*)(ws + WS_SUMS_OFF);
    int*   rowlist  = (int*)(ws + WS_ROWLIST_OFF);

    void* args[] = {
        (void*)&inputs, (void*)&features, (void*)&cluster_mean,
        (void*)&indexes, (void*)&labels, (void*)&targets,
        (void*)&out_logits, (void*)&out_feats, (void*)&out_cm,
        (void*)&new_rows, (void*)&override_, (void*)&hist, (void*)&offs,
        (void*)&fillpos, (void*)&touched, (void*)&sums, (void*)&rowlist
    };
    hipLaunchCooperativeKernel((const void*)mega_kernel, dim3(NBLK), dim3(NTHR),
                               args, 0, stream);
}

// Round 5
// 200.190 us; speedup vs baseline: 3.9098x; 3.9098x over previous
//
#include <hip/hip_runtime.h>

typedef float f32x4 __attribute__((ext_vector_type(4)));

#define B 256
#define D 256
#define N 200000
#define C 1000
#define CM_CHUNKS 8

// ---------------- ws layout (bytes) ----------------
#define WS_NEWROWS_OFF  0          // B*D f32 = 262144
#define WS_SUMS_OFF     262144     // C*D f32 = 1024000   (zeroed region start)
#define WS_HIST_OFF     1286144    // C int   = 4000
#define WS_TOUCHED_OFF  1290144    // C int   = 4000      (zeroed region end)
#define WS_ZERO_BYTES   1032000    // sums + hist + touched, one memset
#define WS_OFFS_OFF     1294144    // C int   = 4000
#define WS_FILLPOS_OFF  1298144    // C int   = 4000
#define WS_ROWLIST_OFF  1302144    // N int   = 800000 -> total 2,102,144

// K1: logits (blk 0..255) || new_rows (blk 256..511) || touched (blk 512)
//     || label histogram (blk 513..1023). All write-disjoint, no intra deps.
__global__ __launch_bounds__(256) void k1_kernel(
    const float* __restrict__ inputs, const float* __restrict__ features,
    const float* __restrict__ cluster_mean, const int* __restrict__ indexes,
    const int* __restrict__ labels, const int* __restrict__ targets,
    float* __restrict__ out_logits, float* __restrict__ new_rows,
    int* __restrict__ hist, int* __restrict__ touched)
{
    const int blk = blockIdx.x;
    const int t = threadIdx.x;

    if (blk < 256) {
        // ---- logits[b,:] = inputs[b] @ cluster_mean.T ----
        __shared__ float sbuf[D];
        int b = blk;
        sbuf[t] = inputs[b * D + t];
        __syncthreads();
        const f32x4* cmv = (const f32x4*)cluster_mean;
        for (int c = t; c < C; c += 256) {
            const f32x4* cm = cmv + (size_t)c * 64;
            float a0 = 0.f, a1 = 0.f, a2 = 0.f, a3 = 0.f;
            #pragma unroll 8
            for (int d4 = 0; d4 < 64; ++d4) {
                f32x4 v = cm[d4];
                const float* si = sbuf + d4 * 4;
                a0 += v.x * si[0];
                a1 += v.y * si[1];
                a2 += v.z * si[2];
                a3 += v.w * si[3];
            }
            out_logits[(size_t)b * C + c] = (a0 + a1) + (a2 + a3);
        }
    } else if (blk < 512) {
        // ---- new_rows[b] = l2norm(0.5*features[indexes[b]] + 0.5*inputs[b]) ----
        __shared__ float wpart[4];
        __shared__ float stot;
        int b = blk - 256;
        int r = indexes[b];
        float x = 0.5f * features[(size_t)r * D + t] + 0.5f * inputs[b * D + t];
        float s = x * x;
        #pragma unroll
        for (int off = 32; off > 0; off >>= 1) s += __shfl_down(s, off);
        if ((t & 63) == 0) wpart[t >> 6] = s;
        __syncthreads();
        if (t == 0) stot = (wpart[0] + wpart[1]) + (wpart[2] + wpart[3]);
        __syncthreads();
        new_rows[b * D + t] = x / sqrtf(stot + 1e-12f);
    } else if (blk == 512) {
        // ---- mark touched clusters ----
        if (t < B) touched[targets[t]] = 1;
    } else {
        // ---- histogram of labels ----
        const int stride = (1024 - 513) * 256;
        for (int i = (blk - 513) * 256 + t; i < N; i += stride)
            atomicAdd(&hist[labels[i]], 1);
    }
}

// K2: patch winner rows into out_feats (blk 0..255) || prefix scan (blk 256)
__global__ __launch_bounds__(256) void k2_kernel(
    const int* __restrict__ indexes, const float* __restrict__ new_rows,
    float* __restrict__ out_feats, const int* __restrict__ hist,
    int* __restrict__ offs, int* __restrict__ fillpos)
{
    const int blk = blockIdx.x;
    const int t = threadIdx.x;

    if (blk < 256) {
        // last-write-wins scatter: block b writes row indexes[b] iff no j>b
        // shares the same index.
        __shared__ int sidx[B];
        __shared__ int lose;
        sidx[t] = indexes[t];
        if (t == 0) lose = 0;
        __syncthreads();
        int b = blk;
        int my = sidx[b];
        if (t > b && sidx[t] == my) lose = 1;
        __syncthreads();
        if (!lose) out_feats[(size_t)my * D + t] = new_rows[b * D + t];
    } else {
        // exclusive prefix scan of hist -> offs, fillpos (256 thr x 4 bins)
        __shared__ int swt[4];
        int base = t * 4;
        int h0 = (base + 0 < C) ? hist[base + 0] : 0;
        int h1 = (base + 1 < C) ? hist[base + 1] : 0;
        int h2 = (base + 2 < C) ? hist[base + 2] : 0;
        int h3 = (base + 3 < C) ? hist[base + 3] : 0;
        int tot = h0 + h1 + h2 + h3;
        int lane = t & 63;
        int scan = tot;
        #pragma unroll
        for (int off = 1; off < 64; off <<= 1) {
            int v = __shfl_up(scan, off);
            if (lane >= off) scan += v;
        }
        if (lane == 63) swt[t >> 6] = scan;
        __syncthreads();
        int wbase = 0;
        for (int i = 0; i < (t >> 6); ++i) wbase += swt[i];
        int excl = wbase + scan - tot;
        if (base + 0 < C) { offs[base + 0] = excl;                fillpos[base + 0] = excl; }
        if (base + 1 < C) { offs[base + 1] = excl + h0;           fillpos[base + 1] = excl + h0; }
        if (base + 2 < C) { offs[base + 2] = excl + h0 + h1;      fillpos[base + 2] = excl + h0 + h1; }
        if (base + 3 < C) { offs[base + 3] = excl + h0 + h1 + h2; fillpos[base + 3] = excl + h0 + h1 + h2; }
    }
}

// K3: scatter row ids of touched clusters into contiguous per-cluster lists.
__global__ __launch_bounds__(256) void fill_kernel(
    const int* __restrict__ labels, const int* __restrict__ touched,
    int* __restrict__ fillpos, int* __restrict__ rowlist)
{
    int i = blockIdx.x * 256 + threadIdx.x;
    if (i >= N) return;
    int lab = labels[i];
    if (touched[lab]) {
        int p = atomicAdd(&fillpos[lab], 1);
        rowlist[p] = i;
    }
}

// K4: parallel cluster sums from the patched out_feats (grid = C*CM_CHUNKS).
__global__ __launch_bounds__(256) void cm_sum_kernel(
    const float* __restrict__ out_feats, const int* __restrict__ touched,
    const int* __restrict__ hist, const int* __restrict__ offs,
    const int* __restrict__ rowlist, float* __restrict__ sums)
{
    int c = blockIdx.x >> 3;      // CM_CHUNKS == 8
    int k = blockIdx.x & 7;
    if (!touched[c]) return;
    int cnt = hist[c];
    if (k >= cnt) return;
    int off = offs[c];
    int t = threadIdx.x;
    float acc = 0.0f;
    for (int j = k; j < cnt; j += CM_CHUNKS)
        acc += out_feats[(size_t)rowlist[off + j] * D + t];
    atomicAdd(&sums[(size_t)c * D + t], acc);
}

// K5: new_cluster_mean[c] = touched ? sums[c]/max(cnt,1) : cluster_mean[c]
__global__ __launch_bounds__(256) void means_kernel(
    const float* __restrict__ cluster_mean, const float* __restrict__ sums,
    const int* __restrict__ hist, const int* __restrict__ touched,
    float* __restrict__ out_cm)
{
    int c = blockIdx.x;
    int t = threadIdx.x;
    float out;
    if (touched[c]) out = sums[(size_t)c * D + t] / fmaxf((float)hist[c], 1.0f);
    else            out = cluster_mean[(size_t)c * D + t];
    out_cm[(size_t)c * D + t] = out;
}

extern "C" void kernel_launch(void* const* d_in, const int* in_sizes, int n_in,
                              void* d_out, int out_size, void* d_ws, size_t ws_size,
                              hipStream_t stream) {
    const float* inputs       = (const float*)d_in[0];
    const float* features     = (const float*)d_in[1];
    const float* cluster_mean = (const float*)d_in[2];
    const int*   indexes      = (const int*)d_in[3];
    const int*   labels       = (const int*)d_in[4];
    const int*   targets      = (const int*)d_in[5];

    float* out_logits = (float*)d_out;                      // B*C
    float* out_feats  = out_logits + (size_t)B * C;         // N*D
    float* out_cm     = out_feats + (size_t)N * D;          // C*D

    char* ws = (char*)d_ws;
    float* new_rows = (float*)(ws + WS_NEWROWS_OFF);
    float* sums     = (float*)(ws + WS_SUMS_OFF);
    int*   hist     = (int*)(ws + WS_HIST_OFF);
    int*   touched  = (int*)(ws + WS_TOUCHED_OFF);
    int*   offs     = (int*)(ws + WS_OFFS_OFF);
    int*   fillpos  = (int*)(ws + WS_FILLPOS_OFF);
    int*   rowlist  = (int*)(ws + WS_ROWLIST_OFF);

    // Bulk copy features -> out_feats on the blit path (~85% HBM peak).
    hipMemcpyAsync(out_feats, features, (size_t)N * D * sizeof(float),
                   hipMemcpyDeviceToDevice, stream);
    // Zero sums + hist + touched in one node.
    hipMemsetAsync(ws + WS_SUMS_OFF, 0, WS_ZERO_BYTES, stream);

    k1_kernel<<<1024, 256, 0, stream>>>(inputs, features, cluster_mean, indexes,
                                        labels, targets, out_logits, new_rows,
                                        hist, touched);
    k2_kernel<<<257, 256, 0, stream>>>(indexes, new_rows, out_feats,
                                       hist, offs, fillpos);
    fill_kernel<<<(N + 255) / 256, 256, 0, stream>>>(labels, touched, fillpos, rowlist);
    cm_sum_kernel<<<C * CM_CHUNKS, 256, 0, stream>>>(out_feats, touched, hist,
                                                     offs, rowlist, sums);
    means_kernel<<<C, 256, 0, stream>>>(cluster_mean, sums, hist, touched, out_cm);
}

// Round 6
// 164.605 us; speedup vs baseline: 4.7550x; 1.2162x over previous
//
#include <hip/hip_runtime.h>

typedef float f32x4 __attribute__((ext_vector_type(4)));

#define B 256
#define D 256
#define N 200000
#define C 1000
#define CM_CHUNKS 8

#define K1_BLOCKS   2048
#define COPY_BLOCKS 1408   // blocks 0..1407: streaming copy
#define LOGITS_LO   1408   // 256 blocks: logits
#define NEWROWS_LO  1664   // 256 blocks: new_rows
#define TOUCH_BLK   1920   // 1 block: touched marks
#define HIST_LO     1921   // 127 blocks: label histogram

// ---------------- ws layout (bytes) ----------------
#define WS_NEWROWS_OFF  0          // B*D f32 = 262144
#define WS_SUMS_OFF     262144     // C*D f32 = 1024000   (zeroed region start)
#define WS_HIST_OFF     1286144    // C int   = 4000
#define WS_TOUCHED_OFF  1290144    // C int   = 4000      (zeroed region end)
#define WS_ZERO_BYTES   1032000    // sums + hist + touched, one memset
#define WS_OFFS_OFF     1294144    // C int   = 4000
#define WS_FILLPOS_OFF  1298144    // C int   = 4000
#define WS_ROWLIST_OFF  1302144    // N int   = 800000 -> total 2,102,144

// K1: streaming copy features->out_feats (blk 0..1407) || logits (1408..1663)
//     || new_rows (1664..1919) || touched (1920) || label hist (1921..2047).
//     All write-disjoint, no intra-kernel ordering needed.
__global__ __launch_bounds__(256) void k1_kernel(
    const float* __restrict__ inputs, const float* __restrict__ features,
    const float* __restrict__ cluster_mean, const int* __restrict__ indexes,
    const int* __restrict__ labels, const int* __restrict__ targets,
    float* __restrict__ out_logits, float* __restrict__ out_feats,
    float* __restrict__ new_rows, int* __restrict__ hist, int* __restrict__ touched)
{
    const int blk = blockIdx.x;
    const int t = threadIdx.x;

    if (blk < COPY_BLOCKS) {
        // ---- bulk copy: N*D floats as f32x4, grid-stride, 2-deep ILP ----
        const f32x4* src = (const f32x4*)features;
        f32x4*       dst = (f32x4*)out_feats;
        const int total4 = N * (D / 4);            // 12,800,000
        const int stride = COPY_BLOCKS * 256;      // 360,448
        int i = blk * 256 + t;
        for (; i + stride < total4; i += 2 * stride) {
            f32x4 v0 = __builtin_nontemporal_load(src + i);
            f32x4 v1 = __builtin_nontemporal_load(src + i + stride);
            dst[i] = v0;
            dst[i + stride] = v1;
        }
        if (i < total4) dst[i] = __builtin_nontemporal_load(src + i);
    } else if (blk < NEWROWS_LO) {
        // ---- logits[b,:] = inputs[b] @ cluster_mean.T ----
        __shared__ float sbuf[D];
        int b = blk - LOGITS_LO;
        sbuf[t] = inputs[b * D + t];
        __syncthreads();
        const f32x4* cmv = (const f32x4*)cluster_mean;
        for (int c = t; c < C; c += 256) {
            const f32x4* cm = cmv + (size_t)c * 64;
            float a0 = 0.f, a1 = 0.f, a2 = 0.f, a3 = 0.f;
            #pragma unroll 8
            for (int d4 = 0; d4 < 64; ++d4) {
                f32x4 v = cm[d4];
                const float* si = sbuf + d4 * 4;
                a0 += v.x * si[0];
                a1 += v.y * si[1];
                a2 += v.z * si[2];
                a3 += v.w * si[3];
            }
            out_logits[(size_t)b * C + c] = (a0 + a1) + (a2 + a3);
        }
    } else if (blk < TOUCH_BLK) {
        // ---- new_rows[b] = l2norm(0.5*features[indexes[b]] + 0.5*inputs[b]) ----
        __shared__ float wpart[4];
        __shared__ float stot;
        int b = blk - NEWROWS_LO;
        int r = indexes[b];
        float x = 0.5f * features[(size_t)r * D + t] + 0.5f * inputs[b * D + t];
        float s = x * x;
        #pragma unroll
        for (int off = 32; off > 0; off >>= 1) s += __shfl_down(s, off);
        if ((t & 63) == 0) wpart[t >> 6] = s;
        __syncthreads();
        if (t == 0) stot = (wpart[0] + wpart[1]) + (wpart[2] + wpart[3]);
        __syncthreads();
        new_rows[b * D + t] = x / sqrtf(stot + 1e-12f);
    } else if (blk == TOUCH_BLK) {
        if (t < B) touched[targets[t]] = 1;
    } else {
        // ---- histogram of labels ----
        const int stride = (K1_BLOCKS - HIST_LO) * 256;
        for (int i = (blk - HIST_LO) * 256 + t; i < N; i += stride)
            atomicAdd(&hist[labels[i]], 1);
    }
}

// K2: patch winner rows into out_feats (blk 0..255) || prefix scan (blk 256)
__global__ __launch_bounds__(256) void k2_kernel(
    const int* __restrict__ indexes, const float* __restrict__ new_rows,
    float* __restrict__ out_feats, const int* __restrict__ hist,
    int* __restrict__ offs, int* __restrict__ fillpos)
{
    const int blk = blockIdx.x;
    const int t = threadIdx.x;

    if (blk < 256) {
        // last-write-wins scatter: block b writes row indexes[b] iff no j>b
        // shares the same index.
        __shared__ int sidx[B];
        __shared__ int lose;
        sidx[t] = indexes[t];
        if (t == 0) lose = 0;
        __syncthreads();
        int b = blk;
        int my = sidx[b];
        if (t > b && sidx[t] == my) lose = 1;
        __syncthreads();
        if (!lose) out_feats[(size_t)my * D + t] = new_rows[b * D + t];
    } else {
        // exclusive prefix scan of hist -> offs, fillpos (256 thr x 4 bins)
        __shared__ int swt[4];
        int base = t * 4;
        int h0 = (base + 0 < C) ? hist[base + 0] : 0;
        int h1 = (base + 1 < C) ? hist[base + 1] : 0;
        int h2 = (base + 2 < C) ? hist[base + 2] : 0;
        int h3 = (base + 3 < C) ? hist[base + 3] : 0;
        int tot = h0 + h1 + h2 + h3;
        int lane = t & 63;
        int scan = tot;
        #pragma unroll
        for (int off = 1; off < 64; off <<= 1) {
            int v = __shfl_up(scan, off);
            if (lane >= off) scan += v;
        }
        if (lane == 63) swt[t >> 6] = scan;
        __syncthreads();
        int wbase = 0;
        for (int i = 0; i < (t >> 6); ++i) wbase += swt[i];
        int excl = wbase + scan - tot;
        if (base + 0 < C) { offs[base + 0] = excl;                fillpos[base + 0] = excl; }
        if (base + 1 < C) { offs[base + 1] = excl + h0;           fillpos[base + 1] = excl + h0; }
        if (base + 2 < C) { offs[base + 2] = excl + h0 + h1;      fillpos[base + 2] = excl + h0 + h1; }
        if (base + 3 < C) { offs[base + 3] = excl + h0 + h1 + h2; fillpos[base + 3] = excl + h0 + h1 + h2; }
    }
}

// K3: scatter row ids of touched clusters into contiguous per-cluster lists.
__global__ __launch_bounds__(256) void fill_kernel(
    const int* __restrict__ labels, const int* __restrict__ touched,
    int* __restrict__ fillpos, int* __restrict__ rowlist)
{
    int i = blockIdx.x * 256 + threadIdx.x;
    if (i >= N) return;
    int lab = labels[i];
    if (touched[lab]) {
        int p = atomicAdd(&fillpos[lab], 1);
        rowlist[p] = i;
    }
}

// K4: parallel cluster sums from the patched out_feats (grid = C*CM_CHUNKS).
__global__ __launch_bounds__(256) void cm_sum_kernel(
    const float* __restrict__ out_feats, const int* __restrict__ touched,
    const int* __restrict__ hist, const int* __restrict__ offs,
    const int* __restrict__ rowlist, float* __restrict__ sums)
{
    int c = blockIdx.x >> 3;      // CM_CHUNKS == 8
    int k = blockIdx.x & 7;
    if (!touched[c]) return;
    int cnt = hist[c];
    if (k >= cnt) return;
    int off = offs[c];
    int t = threadIdx.x;
    float acc = 0.0f;
    for (int j = k; j < cnt; j += CM_CHUNKS)
        acc += out_feats[(size_t)rowlist[off + j] * D + t];
    atomicAdd(&sums[(size_t)c * D + t], acc);
}

// K5: new_cluster_mean[c] = touched ? sums[c]/max(cnt,1) : cluster_mean[c]
__global__ __launch_bounds__(256) void means_kernel(
    const float* __restrict__ cluster_mean, const float* __restrict__ sums,
    const int* __restrict__ hist, const int* __restrict__ touched,
    float* __restrict__ out_cm)
{
    int c = blockIdx.x;
    int t = threadIdx.x;
    float out;
    if (touched[c]) out = sums[(size_t)c * D + t] / fmaxf((float)hist[c], 1.0f);
    else            out = cluster_mean[(size_t)c * D + t];
    out_cm[(size_t)c * D + t] = out;
}

extern "C" void kernel_launch(void* const* d_in, const int* in_sizes, int n_in,
                              void* d_out, int out_size, void* d_ws, size_t ws_size,
                              hipStream_t stream) {
    const float* inputs       = (const float*)d_in[0];
    const float* features     = (const float*)d_in[1];
    const float* cluster_mean = (const float*)d_in[2];
    const int*   indexes      = (const int*)d_in[3];
    const int*   labels       = (const int*)d_in[4];
    const int*   targets      = (const int*)d_in[5];

    float* out_logits = (float*)d_out;                      // B*C
    float* out_feats  = out_logits + (size_t)B * C;         // N*D
    float* out_cm     = out_feats + (size_t)N * D;          // C*D

    char* ws = (char*)d_ws;
    float* new_rows = (float*)(ws + WS_NEWROWS_OFF);
    float* sums     = (float*)(ws + WS_SUMS_OFF);
    int*   hist     = (int*)(ws + WS_HIST_OFF);
    int*   touched  = (int*)(ws + WS_TOUCHED_OFF);
    int*   offs     = (int*)(ws + WS_OFFS_OFF);
    int*   fillpos  = (int*)(ws + WS_FILLPOS_OFF);
    int*   rowlist  = (int*)(ws + WS_ROWLIST_OFF);

    // Zero sums + hist + touched in one node (1.03 MB, ~2 us).
    hipMemsetAsync(ws + WS_SUMS_OFF, 0, WS_ZERO_BYTES, stream);

    k1_kernel<<<K1_BLOCKS, 256, 0, stream>>>(inputs, features, cluster_mean,
                                             indexes, labels, targets,
                                             out_logits, out_feats, new_rows,
                                             hist, touched);
    k2_kernel<<<257, 256, 0, stream>>>(indexes, new_rows, out_feats,
                                       hist, offs, fillpos);
    fill_kernel<<<(N + 255) / 256, 256, 0, stream>>>(labels, touched, fillpos, rowlist);
    cm_sum_kernel<<<C * CM_CHUNKS, 256, 0, stream>>>(out_feats, touched, hist,
                                                     offs, rowlist, sums);
    means_kernel<<<C, 256, 0, stream>>>(cluster_mean, sums, hist, touched, out_cm);
}

// Round 7
// 133.685 us; speedup vs baseline: 5.8548x; 1.2313x over previous
//
#include <hip/hip_runtime.h>

typedef float f32x4 __attribute__((ext_vector_type(4)));

#define B 256
#define D 256
#define N 200000
#define C 1000
#define CM_CHUNKS 8

#define K1_BLOCKS   2048
#define LOGITS_LO   0      // 256 blocks: logits
#define NEWROWS_LO  256    // 256 blocks: new_rows
#define TOUCH_BLK   512    // 1 block: touched marks
#define HIST_LO     513    // 64 blocks: LDS-privatized label histogram
#define HIST_BLOCKS 64
#define COPY_LO     577    // 1471 blocks: streaming copy
#define COPY_BLOCKS (K1_BLOCKS - COPY_LO)

// ---------------- ws layout (bytes) ----------------
#define WS_NEWROWS_OFF  0          // B*D f32 = 262144
#define WS_SUMS_OFF     262144     // C*D f32 = 1024000   (zeroed region start)
#define WS_HIST_OFF     1286144    // C int   = 4000
#define WS_TOUCHED_OFF  1290144    // C int   = 4000      (zeroed region end)
#define WS_OFFS_OFF     1294144    // C int   = 4000
#define WS_FILLPOS_OFF  1298144    // C int   = 4000
#define WS_ROWLIST_OFF  1302144    // N int   = 800000 -> total 2,102,144
#define ZERO_WORDS      (C * D + C + C)   // sums + hist + touched = 258,000 ints

// K0: zero sums + hist + touched (shader fill; memset node timestamps were junk)
__global__ __launch_bounds__(256) void k0_zero(int* __restrict__ z) {
    int i = blockIdx.x * 256 + threadIdx.x;
    if (i < ZERO_WORDS) z[i] = 0;
}

// K1: logits (0..255) || new_rows (256..511) || touched (512) || hist (513..576)
//     || streaming copy features->out_feats with NT stores (577..2047).
//     All write-disjoint, no intra-kernel ordering needed.
__global__ __launch_bounds__(256) void k1_kernel(
    const float* __restrict__ inputs, const float* __restrict__ features,
    const float* __restrict__ cluster_mean, const int* __restrict__ indexes,
    const int* __restrict__ labels, const int* __restrict__ targets,
    float* __restrict__ out_logits, float* __restrict__ out_feats,
    float* __restrict__ new_rows, int* __restrict__ hist, int* __restrict__ touched)
{
    const int blk = blockIdx.x;
    const int t = threadIdx.x;

    __shared__ float sbuf[D];     // logits input row
    __shared__ float wpart[4];    // new_rows partials
    __shared__ float stot;
    __shared__ int   lh[C];       // local histogram

    if (blk >= COPY_LO) {
        // ---- bulk copy: cached loads (MALL-resident), nontemporal stores ----
        const f32x4* src = (const f32x4*)features;
        f32x4*       dst = (f32x4*)out_feats;
        const int total4 = N * (D / 4);            // 12,800,000
        const int stride = COPY_BLOCKS * 256;      // 376,576
        int i = (blk - COPY_LO) * 256 + t;
        for (; i + stride < total4; i += 2 * stride) {
            f32x4 v0 = src[i];
            f32x4 v1 = src[i + stride];
            __builtin_nontemporal_store(v0, dst + i);
            __builtin_nontemporal_store(v1, dst + i + stride);
        }
        if (i < total4) __builtin_nontemporal_store(src[i], dst + i);
    } else if (blk < NEWROWS_LO) {
        // ---- logits[b,:] = inputs[b] @ cluster_mean.T ----
        int b = blk - LOGITS_LO;
        sbuf[t] = inputs[b * D + t];
        __syncthreads();
        const f32x4* cmv = (const f32x4*)cluster_mean;
        for (int c = t; c < C; c += 256) {
            const f32x4* cm = cmv + (size_t)c * 64;
            float a0 = 0.f, a1 = 0.f, a2 = 0.f, a3 = 0.f;
            #pragma unroll 8
            for (int d4 = 0; d4 < 64; ++d4) {
                f32x4 v = cm[d4];
                const float* si = sbuf + d4 * 4;
                a0 += v.x * si[0];
                a1 += v.y * si[1];
                a2 += v.z * si[2];
                a3 += v.w * si[3];
            }
            out_logits[(size_t)b * C + c] = (a0 + a1) + (a2 + a3);
        }
    } else if (blk < TOUCH_BLK) {
        // ---- new_rows[b] = l2norm(0.5*features[indexes[b]] + 0.5*inputs[b]) ----
        int b = blk - NEWROWS_LO;
        int r = indexes[b];
        float x = 0.5f * features[(size_t)r * D + t] + 0.5f * inputs[b * D + t];
        float s = x * x;
        #pragma unroll
        for (int off = 32; off > 0; off >>= 1) s += __shfl_down(s, off);
        if ((t & 63) == 0) wpart[t >> 6] = s;
        __syncthreads();
        if (t == 0) stot = (wpart[0] + wpart[1]) + (wpart[2] + wpart[3]);
        __syncthreads();
        new_rows[b * D + t] = x / sqrtf(stot + 1e-12f);
    } else if (blk == TOUCH_BLK) {
        if (t < B) touched[targets[t]] = 1;
    } else {
        // ---- label histogram, LDS-privatized ----
        for (int i = t; i < C; i += 256) lh[i] = 0;
        __syncthreads();
        const int stride = HIST_BLOCKS * 256;
        for (int i = (blk - HIST_LO) * 256 + t; i < N; i += stride)
            atomicAdd(&lh[labels[i]], 1);
        __syncthreads();
        for (int i = t; i < C; i += 256) {
            int v = lh[i];
            if (v) atomicAdd(&hist[i], v);
        }
    }
}

// K2: patch winner rows into out_feats (blk 0..255) || prefix scan (blk 256)
__global__ __launch_bounds__(256) void k2_kernel(
    const int* __restrict__ indexes, const float* __restrict__ new_rows,
    float* __restrict__ out_feats, const int* __restrict__ hist,
    int* __restrict__ offs, int* __restrict__ fillpos)
{
    const int blk = blockIdx.x;
    const int t = threadIdx.x;

    if (blk < 256) {
        // last-write-wins scatter: block b writes row indexes[b] iff no j>b
        // shares the same index.
        __shared__ int sidx[B];
        __shared__ int lose;
        sidx[t] = indexes[t];
        if (t == 0) lose = 0;
        __syncthreads();
        int b = blk;
        int my = sidx[b];
        if (t > b && sidx[t] == my) lose = 1;
        __syncthreads();
        if (!lose) out_feats[(size_t)my * D + t] = new_rows[b * D + t];
    } else {
        // exclusive prefix scan of hist -> offs, fillpos (256 thr x 4 bins)
        __shared__ int swt[4];
        int base = t * 4;
        int h0 = (base + 0 < C) ? hist[base + 0] : 0;
        int h1 = (base + 1 < C) ? hist[base + 1] : 0;
        int h2 = (base + 2 < C) ? hist[base + 2] : 0;
        int h3 = (base + 3 < C) ? hist[base + 3] : 0;
        int tot = h0 + h1 + h2 + h3;
        int lane = t & 63;
        int scan = tot;
        #pragma unroll
        for (int off = 1; off < 64; off <<= 1) {
            int v = __shfl_up(scan, off);
            if (lane >= off) scan += v;
        }
        if (lane == 63) swt[t >> 6] = scan;
        __syncthreads();
        int wbase = 0;
        for (int i = 0; i < (t >> 6); ++i) wbase += swt[i];
        int excl = wbase + scan - tot;
        if (base + 0 < C) { offs[base + 0] = excl;                fillpos[base + 0] = excl; }
        if (base + 1 < C) { offs[base + 1] = excl + h0;           fillpos[base + 1] = excl + h0; }
        if (base + 2 < C) { offs[base + 2] = excl + h0 + h1;      fillpos[base + 2] = excl + h0 + h1; }
        if (base + 3 < C) { offs[base + 3] = excl + h0 + h1 + h2; fillpos[base + 3] = excl + h0 + h1 + h2; }
    }
}

// K3: scatter row ids of touched clusters into contiguous per-cluster lists.
__global__ __launch_bounds__(256) void fill_kernel(
    const int* __restrict__ labels, const int* __restrict__ touched,
    int* __restrict__ fillpos, int* __restrict__ rowlist)
{
    int i = blockIdx.x * 256 + threadIdx.x;
    if (i >= N) return;
    int lab = labels[i];
    if (touched[lab]) {
        int p = atomicAdd(&fillpos[lab], 1);
        rowlist[p] = i;
    }
}

// K4: parallel cluster sums from the patched out_feats (grid = C*CM_CHUNKS).
__global__ __launch_bounds__(256) void cm_sum_kernel(
    const float* __restrict__ out_feats, const int* __restrict__ touched,
    const int* __restrict__ hist, const int* __restrict__ offs,
    const int* __restrict__ rowlist, float* __restrict__ sums)
{
    int c = blockIdx.x >> 3;      // CM_CHUNKS == 8
    int k = blockIdx.x & 7;
    if (!touched[c]) return;
    int cnt = hist[c];
    if (k >= cnt) return;
    int off = offs[c];
    int t = threadIdx.x;
    float acc = 0.0f;
    for (int j = k; j < cnt; j += CM_CHUNKS)
        acc += out_feats[(size_t)rowlist[off + j] * D + t];
    atomicAdd(&sums[(size_t)c * D + t], acc);
}

// K5: new_cluster_mean[c] = touched ? sums[c]/max(cnt,1) : cluster_mean[c]
__global__ __launch_bounds__(256) void means_kernel(
    const float* __restrict__ cluster_mean, const float* __restrict__ sums,
    const int* __restrict__ hist, const int* __restrict__ touched,
    float* __restrict__ out_cm)
{
    int c = blockIdx.x;
    int t = threadIdx.x;
    float out;
    if (touched[c]) out = sums[(size_t)c * D + t] / fmaxf((float)hist[c], 1.0f);
    else            out = cluster_mean[(size_t)c * D + t];
    out_cm[(size_t)c * D + t] = out;
}

extern "C" void kernel_launch(void* const* d_in, const int* in_sizes, int n_in,
                              void* d_out, int out_size, void* d_ws, size_t ws_size,
                              hipStream_t stream) {
    const float* inputs       = (const float*)d_in[0];
    const float* features     = (const float*)d_in[1];
    const float* cluster_mean = (const float*)d_in[2];
    const int*   indexes      = (const int*)d_in[3];
    const int*   labels       = (const int*)d_in[4];
    const int*   targets      = (const int*)d_in[5];

    float* out_logits = (float*)d_out;                      // B*C
    float* out_feats  = out_logits + (size_t)B * C;         // N*D
    float* out_cm     = out_feats + (size_t)N * D;          // C*D

    char* ws = (char*)d_ws;
    float* new_rows = (float*)(ws + WS_NEWROWS_OFF);
    float* sums     = (float*)(ws + WS_SUMS_OFF);
    int*   hist     = (int*)(ws + WS_HIST_OFF);
    int*   touched  = (int*)(ws + WS_TOUCHED_OFF);
    int*   offs     = (int*)(ws + WS_OFFS_OFF);
    int*   fillpos  = (int*)(ws + WS_FILLPOS_OFF);
    int*   rowlist  = (int*)(ws + WS_ROWLIST_OFF);

    k0_zero<<<(ZERO_WORDS + 255) / 256, 256, 0, stream>>>((int*)(ws + WS_SUMS_OFF));
    k1_kernel<<<K1_BLOCKS, 256, 0, stream>>>(inputs, features, cluster_mean,
                                             indexes, labels, targets,
                                             out_logits, out_feats, new_rows,
                                             hist, touched);
    k2_kernel<<<257, 256, 0, stream>>>(indexes, new_rows, out_feats,
                                       hist, offs, fillpos);
    fill_kernel<<<(N + 255) / 256, 256, 0, stream>>>(labels, touched, fillpos, rowlist);
    cm_sum_kernel<<<C * CM_CHUNKS, 256, 0, stream>>>(out_feats, touched, hist,
                                                     offs, rowlist, sums);
    means_kernel<<<C, 256, 0, stream>>>(cluster_mean, sums, hist, touched, out_cm);
}

// Round 8
// 125.299 us; speedup vs baseline: 6.2467x; 1.0669x over previous
//
#include <hip/hip_runtime.h>

typedef float f32x4 __attribute__((ext_vector_type(4)));

#define B 256
#define D 256
#define N 200000
#define C 1000

#define K1_BLOCKS   2048
#define LOGITS_LO   0      // 256 blocks: logits
#define NEWROWS_LO  256    // 256 blocks: new_rows
#define TOUCH_BLK   512    // 1 block: touched marks
#define HIST_LO     513    // 64 blocks: LDS-privatized label histogram
#define HIST_BLOCKS 64
#define COPY_LO     577    // 1471 blocks: streaming copy
#define COPY_BLOCKS (K1_BLOCKS - COPY_LO)

// ---------------- ws layout (bytes) ----------------
#define WS_NEWROWS_OFF  0          // B*D f32 = 262144
#define WS_HIST_OFF     262144     // C int   = 4000   (zeroed region start)
#define WS_TOUCHED_OFF  266144     // C int   = 4000   (zeroed region end)
#define WS_OFFS_OFF     270144     // C int   = 4000
#define WS_FILLPOS_OFF  274144     // C int   = 4000
#define WS_ROWLIST_OFF  278144     // N int   = 800000 -> total 1,078,144
#define ZERO_WORDS      (2 * C)    // hist + touched

// K0: zero hist + touched (2000 ints; ws is poisoned 0xAA, never re-poisoned)
__global__ __launch_bounds__(256) void k0_zero(int* __restrict__ z) {
    int i = blockIdx.x * 256 + threadIdx.x;
    if (i < ZERO_WORDS) z[i] = 0;
}

// K1: logits (0..255) || new_rows (256..511) || touched (512) || hist (513..576)
//     || streaming copy features->out_feats, cached loads + NT stores (577..2047).
//     All write-disjoint, no intra-kernel ordering needed.
//     NT stores keep `features` MALL-resident across graph replays (timed runs
//     are much faster than rocprof's cold replays — R7 post-mortem).
__global__ __launch_bounds__(256) void k1_kernel(
    const float* __restrict__ inputs, const float* __restrict__ features,
    const float* __restrict__ cluster_mean, const int* __restrict__ indexes,
    const int* __restrict__ labels, const int* __restrict__ targets,
    float* __restrict__ out_logits, float* __restrict__ out_feats,
    float* __restrict__ new_rows, int* __restrict__ hist, int* __restrict__ touched)
{
    const int blk = blockIdx.x;
    const int t = threadIdx.x;

    if (blk >= COPY_LO) {
        // ---- bulk copy, ILP-4 ----
        const f32x4* src = (const f32x4*)features;
        f32x4*       dst = (f32x4*)out_feats;
        const int total4 = N * (D / 4);            // 12,800,000
        const int stride = COPY_BLOCKS * 256;      // 376,576
        int i = (blk - COPY_LO) * 256 + t;
        for (; i + 3 * stride < total4; i += 4 * stride) {
            f32x4 v0 = src[i];
            f32x4 v1 = src[i + stride];
            f32x4 v2 = src[i + 2 * stride];
            f32x4 v3 = src[i + 3 * stride];
            __builtin_nontemporal_store(v0, dst + i);
            __builtin_nontemporal_store(v1, dst + i + stride);
            __builtin_nontemporal_store(v2, dst + i + 2 * stride);
            __builtin_nontemporal_store(v3, dst + i + 3 * stride);
        }
        for (; i < total4; i += stride)
            __builtin_nontemporal_store(src[i], dst + i);
    } else if (blk < NEWROWS_LO) {
        // ---- logits[b,:] = inputs[b] @ cluster_mean.T ----
        __shared__ float sbuf[D];
        int b = blk - LOGITS_LO;
        sbuf[t] = inputs[b * D + t];
        __syncthreads();
        const f32x4* cmv = (const f32x4*)cluster_mean;
        for (int c = t; c < C; c += 256) {
            const f32x4* cm = cmv + (size_t)c * 64;
            float a0 = 0.f, a1 = 0.f, a2 = 0.f, a3 = 0.f;
            #pragma unroll 8
            for (int d4 = 0; d4 < 64; ++d4) {
                f32x4 v = cm[d4];
                const float* si = sbuf + d4 * 4;
                a0 += v.x * si[0];
                a1 += v.y * si[1];
                a2 += v.z * si[2];
                a3 += v.w * si[3];
            }
            out_logits[(size_t)b * C + c] = (a0 + a1) + (a2 + a3);
        }
    } else if (blk < TOUCH_BLK) {
        // ---- new_rows[b] = l2norm(0.5*features[indexes[b]] + 0.5*inputs[b]) ----
        __shared__ float wpart[4];
        __shared__ float stot;
        int b = blk - NEWROWS_LO;
        int r = indexes[b];
        float x = 0.5f * features[(size_t)r * D + t] + 0.5f * inputs[b * D + t];
        float s = x * x;
        #pragma unroll
        for (int off = 32; off > 0; off >>= 1) s += __shfl_down(s, off);
        if ((t & 63) == 0) wpart[t >> 6] = s;
        __syncthreads();
        if (t == 0) stot = (wpart[0] + wpart[1]) + (wpart[2] + wpart[3]);
        __syncthreads();
        new_rows[b * D + t] = x / sqrtf(stot + 1e-12f);
    } else if (blk == TOUCH_BLK) {
        if (t < B) touched[targets[t]] = 1;
    } else {
        // ---- label histogram, LDS-privatized ----
        __shared__ int lh[C];
        for (int i = t; i < C; i += 256) lh[i] = 0;
        __syncthreads();
        const int stride = HIST_BLOCKS * 256;
        for (int i = (blk - HIST_LO) * 256 + t; i < N; i += stride)
            atomicAdd(&lh[labels[i]], 1);
        __syncthreads();
        for (int i = t; i < C; i += 256) {
            int v = lh[i];
            if (v) atomicAdd(&hist[i], v);
        }
    }
}

// K2: patch winner rows into out_feats (blk 0..255) || prefix scan (blk 256)
__global__ __launch_bounds__(256) void k2_kernel(
    const int* __restrict__ indexes, const float* __restrict__ new_rows,
    float* __restrict__ out_feats, const int* __restrict__ hist,
    int* __restrict__ offs, int* __restrict__ fillpos)
{
    const int blk = blockIdx.x;
    const int t = threadIdx.x;

    if (blk < 256) {
        // last-write-wins scatter: block b writes row indexes[b] iff no j>b
        // shares the same index.
        __shared__ int sidx[B];
        __shared__ int lose;
        sidx[t] = indexes[t];
        if (t == 0) lose = 0;
        __syncthreads();
        int b = blk;
        int my = sidx[b];
        if (t > b && sidx[t] == my) lose = 1;
        __syncthreads();
        if (!lose) out_feats[(size_t)my * D + t] = new_rows[b * D + t];
    } else {
        // exclusive prefix scan of hist -> offs, fillpos (256 thr x 4 bins)
        __shared__ int swt[4];
        int base = t * 4;
        int h0 = (base + 0 < C) ? hist[base + 0] : 0;
        int h1 = (base + 1 < C) ? hist[base + 1] : 0;
        int h2 = (base + 2 < C) ? hist[base + 2] : 0;
        int h3 = (base + 3 < C) ? hist[base + 3] : 0;
        int tot = h0 + h1 + h2 + h3;
        int lane = t & 63;
        int scan = tot;
        #pragma unroll
        for (int off = 1; off < 64; off <<= 1) {
            int v = __shfl_up(scan, off);
            if (lane >= off) scan += v;
        }
        if (lane == 63) swt[t >> 6] = scan;
        __syncthreads();
        int wbase = 0;
        for (int i = 0; i < (t >> 6); ++i) wbase += swt[i];
        int excl = wbase + scan - tot;
        if (base + 0 < C) { offs[base + 0] = excl;                fillpos[base + 0] = excl; }
        if (base + 1 < C) { offs[base + 1] = excl + h0;           fillpos[base + 1] = excl + h0; }
        if (base + 2 < C) { offs[base + 2] = excl + h0 + h1;      fillpos[base + 2] = excl + h0 + h1; }
        if (base + 3 < C) { offs[base + 3] = excl + h0 + h1 + h2; fillpos[base + 3] = excl + h0 + h1 + h2; }
    }
}

// K3: scatter row ids of touched clusters into contiguous per-cluster lists.
__global__ __launch_bounds__(256) void fill_kernel(
    const int* __restrict__ labels, const int* __restrict__ touched,
    int* __restrict__ fillpos, int* __restrict__ rowlist)
{
    int i = blockIdx.x * 256 + threadIdx.x;
    if (i >= N) return;
    int lab = labels[i];
    if (touched[lab]) {
        int p = atomicAdd(&fillpos[lab], 1);
        rowlist[p] = i;
    }
}

// K4: fused cluster mean. One block (1024 thr = 4 k-chunks x 256 d) per cluster.
// Touched: sum row list from patched out_feats (atomic-free, LDS reduce), divide,
// write. Untouched: copy cluster_mean.
__global__ __launch_bounds__(1024) void cm_kernel(
    const float* __restrict__ cluster_mean, const float* __restrict__ out_feats,
    const int* __restrict__ touched, const int* __restrict__ hist,
    const int* __restrict__ offs, const int* __restrict__ rowlist,
    float* __restrict__ out_cm)
{
    const int c = blockIdx.x;
    const int d = threadIdx.x & 255;
    const int k = threadIdx.x >> 8;     // 0..3
    if (!touched[c]) {                  // block-uniform branch
        if (k == 0) out_cm[(size_t)c * D + d] = cluster_mean[(size_t)c * D + d];
        return;
    }
    __shared__ float red[3][256];
    const int cnt = hist[c];
    const int off = offs[c];
    float acc = 0.0f;
    #pragma unroll 4
    for (int j = k; j < cnt; j += 4)
        acc += out_feats[(size_t)rowlist[off + j] * D + d];
    if (k > 0) red[k - 1][d] = acc;
    __syncthreads();
    if (k == 0) {
        float tot = acc + red[0][d] + red[1][d] + red[2][d];
        out_cm[(size_t)c * D + d] = tot / fmaxf((float)cnt, 1.0f);
    }
}

extern "C" void kernel_launch(void* const* d_in, const int* in_sizes, int n_in,
                              void* d_out, int out_size, void* d_ws, size_t ws_size,
                              hipStream_t stream) {
    const float* inputs       = (const float*)d_in[0];
    const float* features     = (const float*)d_in[1];
    const float* cluster_mean = (const float*)d_in[2];
    const int*   indexes      = (const int*)d_in[3];
    const int*   labels       = (const int*)d_in[4];
    const int*   targets      = (const int*)d_in[5];

    float* out_logits = (float*)d_out;                      // B*C
    float* out_feats  = out_logits + (size_t)B * C;         // N*D
    float* out_cm     = out_feats + (size_t)N * D;          // C*D

    char* ws = (char*)d_ws;
    float* new_rows = (float*)(ws + WS_NEWROWS_OFF);
    int*   hist     = (int*)(ws + WS_HIST_OFF);
    int*   touched  = (int*)(ws + WS_TOUCHED_OFF);
    int*   offs     = (int*)(ws + WS_OFFS_OFF);
    int*   fillpos  = (int*)(ws + WS_FILLPOS_OFF);
    int*   rowlist  = (int*)(ws + WS_ROWLIST_OFF);

    k0_zero<<<(ZERO_WORDS + 255) / 256, 256, 0, stream>>>((int*)(ws + WS_HIST_OFF));
    k1_kernel<<<K1_BLOCKS, 256, 0, stream>>>(inputs, features, cluster_mean,
                                             indexes, labels, targets,
                                             out_logits, out_feats, new_rows,
                                             hist, touched);
    k2_kernel<<<257, 256, 0, stream>>>(indexes, new_rows, out_feats,
                                       hist, offs, fillpos);
    fill_kernel<<<(N + 255) / 256, 256, 0, stream>>>(labels, touched, fillpos, rowlist);
    cm_kernel<<<C, 1024, 0, stream>>>(cluster_mean, out_feats, touched, hist,
                                      offs, rowlist, out_cm);
}

// Round 9
// 124.707 us; speedup vs baseline: 6.2763x; 1.0047x over previous
//
#include <hip/hip_runtime.h>

typedef float f32x4 __attribute__((ext_vector_type(4)));

#define B 256
#define D 256
#define N 200000
#define C 1000

#define K1_BLOCKS   2048
#define LOGITS_LO   0      // 256 blocks: logits
#define NEWROWS_LO  256    // 256 blocks: new_rows
#define TOUCH_BLK   512    // 1 block: touched marks
#define HIST_LO     513    // 64 blocks: LDS-privatized label histogram
#define HIST_BLOCKS 64
#define COPY_LO     577    // 1471 blocks: streaming copy
#define COPY_BLOCKS (K1_BLOCKS - COPY_LO)

// ---------------- ws layout (bytes) ----------------
#define WS_NEWROWS_OFF  0          // B*D f32 = 262144
#define WS_HIST_OFF     262144     // C int = 4000   (zeroed region start)
#define WS_TOUCHED_OFF  266144     // C int = 4000
#define WS_NW_OFF       270144     // 1 int          (zeroed region end)
#define WS_OFFS_OFF     270148     // C int = 4000
#define WS_FILLPOS_OFF  274148     // C int = 4000
#define WS_WROW_OFF     278148     // B int = 1024
#define WS_WLAB_OFF     279172     // B int = 1024
#define WS_WB_OFF       280196     // B int = 1024
#define WS_ROWLIST_OFF  281220     // N int = 800000 -> total 1,081,220
#define ZERO_WORDS      (2 * C + 1)  // hist + touched + nw (contiguous)

// K0: zero hist + touched + nw (ws is poisoned 0xAA, never re-poisoned)
__global__ __launch_bounds__(256) void k0_zero(int* __restrict__ z) {
    int i = blockIdx.x * 256 + threadIdx.x;
    if (i < ZERO_WORDS) z[i] = 0;
}

// K1: logits (0..255) || new_rows (256..511) || touched (512) || hist (513..576)
//     || streaming copy features->out_feats, cached loads + NT stores (577..2047).
//     NT stores keep `features` MALL-resident across graph replays; with nothing
//     ever reading out_feats, steady-state K1 is a pure HBM write stream.
__global__ __launch_bounds__(256) void k1_kernel(
    const float* __restrict__ inputs, const float* __restrict__ features,
    const float* __restrict__ cluster_mean, const int* __restrict__ indexes,
    const int* __restrict__ labels, const int* __restrict__ targets,
    float* __restrict__ out_logits, float* __restrict__ out_feats,
    float* __restrict__ new_rows, int* __restrict__ hist, int* __restrict__ touched)
{
    const int blk = blockIdx.x;
    const int t = threadIdx.x;

    if (blk >= COPY_LO) {
        // ---- bulk copy, ILP-4, cached loads (L3-hit warm) + NT stores ----
        const f32x4* src = (const f32x4*)features;
        f32x4*       dst = (f32x4*)out_feats;
        const int total4 = N * (D / 4);            // 12,800,000
        const int stride = COPY_BLOCKS * 256;      // 376,576
        int i = (blk - COPY_LO) * 256 + t;
        for (; i + 3 * stride < total4; i += 4 * stride) {
            f32x4 v0 = src[i];
            f32x4 v1 = src[i + stride];
            f32x4 v2 = src[i + 2 * stride];
            f32x4 v3 = src[i + 3 * stride];
            __builtin_nontemporal_store(v0, dst + i);
            __builtin_nontemporal_store(v1, dst + i + stride);
            __builtin_nontemporal_store(v2, dst + i + 2 * stride);
            __builtin_nontemporal_store(v3, dst + i + 3 * stride);
        }
        for (; i < total4; i += stride)
            __builtin_nontemporal_store(src[i], dst + i);
    } else if (blk < NEWROWS_LO) {
        // ---- logits[b,:] = inputs[b] @ cluster_mean.T ----
        __shared__ float sbuf[D];
        int b = blk - LOGITS_LO;
        sbuf[t] = inputs[b * D + t];
        __syncthreads();
        const f32x4* cmv = (const f32x4*)cluster_mean;
        for (int c = t; c < C; c += 256) {
            const f32x4* cm = cmv + (size_t)c * 64;
            float a0 = 0.f, a1 = 0.f, a2 = 0.f, a3 = 0.f;
            #pragma unroll 8
            for (int d4 = 0; d4 < 64; ++d4) {
                f32x4 v = cm[d4];
                const float* si = sbuf + d4 * 4;
                a0 += v.x * si[0];
                a1 += v.y * si[1];
                a2 += v.z * si[2];
                a3 += v.w * si[3];
            }
            out_logits[(size_t)b * C + c] = (a0 + a1) + (a2 + a3);
        }
    } else if (blk < TOUCH_BLK) {
        // ---- new_rows[b] = l2norm(0.5*features[indexes[b]] + 0.5*inputs[b]) ----
        __shared__ float wpart[4];
        __shared__ float stot;
        int b = blk - NEWROWS_LO;
        int r = indexes[b];
        float x = 0.5f * features[(size_t)r * D + t] + 0.5f * inputs[b * D + t];
        float s = x * x;
        #pragma unroll
        for (int off = 32; off > 0; off >>= 1) s += __shfl_down(s, off);
        if ((t & 63) == 0) wpart[t >> 6] = s;
        __syncthreads();
        if (t == 0) stot = (wpart[0] + wpart[1]) + (wpart[2] + wpart[3]);
        __syncthreads();
        new_rows[b * D + t] = x / sqrtf(stot + 1e-12f);
    } else if (blk == TOUCH_BLK) {
        if (t < B) touched[targets[t]] = 1;
    } else {
        // ---- label histogram, LDS-privatized ----
        __shared__ int lh[C];
        for (int i = t; i < C; i += 256) lh[i] = 0;
        __syncthreads();
        const int stride = HIST_BLOCKS * 256;
        for (int i = (blk - HIST_LO) * 256 + t; i < N; i += stride)
            atomicAdd(&lh[labels[i]], 1);
        __syncthreads();
        for (int i = t; i < C; i += 256) {
            int v = lh[i];
            if (v) atomicAdd(&hist[i], v);
        }
    }
}

// K2: patch winner rows into out_feats + append winner metadata (blk 0..255)
//     || prefix scan (blk 256)
__global__ __launch_bounds__(256) void k2_kernel(
    const int* __restrict__ indexes, const int* __restrict__ labels,
    const float* __restrict__ new_rows, float* __restrict__ out_feats,
    const int* __restrict__ hist, int* __restrict__ offs, int* __restrict__ fillpos,
    int* __restrict__ nw, int* __restrict__ w_row, int* __restrict__ w_lab,
    int* __restrict__ w_b)
{
    const int blk = blockIdx.x;
    const int t = threadIdx.x;

    if (blk < 256) {
        // last-write-wins: block b writes row indexes[b] iff no j>b shares it.
        __shared__ int sidx[B];
        __shared__ int lose;
        sidx[t] = indexes[t];
        if (t == 0) lose = 0;
        __syncthreads();
        int b = blk;
        int my = sidx[b];
        if (t > b && sidx[t] == my) lose = 1;
        __syncthreads();
        if (!lose) {
            __builtin_nontemporal_store(new_rows[b * D + t], &out_feats[(size_t)my * D + t]);
            if (t == 0) {
                int p = atomicAdd(nw, 1);
                w_row[p] = my;
                w_lab[p] = labels[my];
                w_b[p] = b;
            }
        }
    } else {
        // exclusive prefix scan of hist -> offs, fillpos (256 thr x 4 bins)
        __shared__ int swt[4];
        int base = t * 4;
        int h0 = (base + 0 < C) ? hist[base + 0] : 0;
        int h1 = (base + 1 < C) ? hist[base + 1] : 0;
        int h2 = (base + 2 < C) ? hist[base + 2] : 0;
        int h3 = (base + 3 < C) ? hist[base + 3] : 0;
        int tot = h0 + h1 + h2 + h3;
        int lane = t & 63;
        int scan = tot;
        #pragma unroll
        for (int off = 1; off < 64; off <<= 1) {
            int v = __shfl_up(scan, off);
            if (lane >= off) scan += v;
        }
        if (lane == 63) swt[t >> 6] = scan;
        __syncthreads();
        int wbase = 0;
        for (int i = 0; i < (t >> 6); ++i) wbase += swt[i];
        int excl = wbase + scan - tot;
        if (base + 0 < C) { offs[base + 0] = excl;                fillpos[base + 0] = excl; }
        if (base + 1 < C) { offs[base + 1] = excl + h0;           fillpos[base + 1] = excl + h0; }
        if (base + 2 < C) { offs[base + 2] = excl + h0 + h1;      fillpos[base + 2] = excl + h0 + h1; }
        if (base + 3 < C) { offs[base + 3] = excl + h0 + h1 + h2; fillpos[base + 3] = excl + h0 + h1 + h2; }
    }
}

// K3: scatter row ids of touched clusters into contiguous per-cluster lists.
__global__ __launch_bounds__(256) void fill_kernel(
    const int* __restrict__ labels, const int* __restrict__ touched,
    int* __restrict__ fillpos, int* __restrict__ rowlist)
{
    int i = blockIdx.x * 256 + threadIdx.x;
    if (i >= N) return;
    int lab = labels[i];
    if (touched[lab]) {
        int p = atomicAdd(&fillpos[lab], 1);
        rowlist[p] = i;
    }
}

// K4: cluster mean WITHOUT touching out_feats: sum features rows (L3-hot) and
// algebraically correct for patched rows:
//   sum = sum_{r in c} features[r] + sum_{winners w: lab_w==c} (new_rows[w] - features[row_w])
__global__ __launch_bounds__(1024) void cm_kernel(
    const float* __restrict__ cluster_mean, const float* __restrict__ features,
    const float* __restrict__ new_rows, const int* __restrict__ touched,
    const int* __restrict__ hist, const int* __restrict__ offs,
    const int* __restrict__ rowlist, const int* __restrict__ nw,
    const int* __restrict__ w_row, const int* __restrict__ w_lab,
    const int* __restrict__ w_b, float* __restrict__ out_cm)
{
    const int c = blockIdx.x;
    const int d = threadIdx.x & 255;
    const int k = threadIdx.x >> 8;     // 0..3
    if (!touched[c]) {                  // block-uniform branch
        if (k == 0) out_cm[(size_t)c * D + d] = cluster_mean[(size_t)c * D + d];
        return;
    }
    __shared__ float red[3][256];
    const int cnt = hist[c];
    const int off = offs[c];
    float acc = 0.0f;
    #pragma unroll 4
    for (int j = k; j < cnt; j += 4)
        acc += features[(size_t)rowlist[off + j] * D + d];
    // winner correction, distributed over k-chunks (block-uniform inner test)
    const int nwv = *nw;
    for (int j = k; j < nwv; j += 4) {
        if (w_lab[j] == c)
            acc += new_rows[w_b[j] * D + d] - features[(size_t)w_row[j] * D + d];
    }
    if (k > 0) red[k - 1][d] = acc;
    __syncthreads();
    if (k == 0) {
        float tot = acc + red[0][d] + red[1][d] + red[2][d];
        out_cm[(size_t)c * D + d] = tot / fmaxf((float)cnt, 1.0f);
    }
}

extern "C" void kernel_launch(void* const* d_in, const int* in_sizes, int n_in,
                              void* d_out, int out_size, void* d_ws, size_t ws_size,
                              hipStream_t stream) {
    const float* inputs       = (const float*)d_in[0];
    const float* features     = (const float*)d_in[1];
    const float* cluster_mean = (const float*)d_in[2];
    const int*   indexes      = (const int*)d_in[3];
    const int*   labels       = (const int*)d_in[4];
    const int*   targets      = (const int*)d_in[5];

    float* out_logits = (float*)d_out;                      // B*C
    float* out_feats  = out_logits + (size_t)B * C;         // N*D
    float* out_cm     = out_feats + (size_t)N * D;          // C*D

    char* ws = (char*)d_ws;
    float* new_rows = (float*)(ws + WS_NEWROWS_OFF);
    int*   hist     = (int*)(ws + WS_HIST_OFF);
    int*   touched  = (int*)(ws + WS_TOUCHED_OFF);
    int*   nw       = (int*)(ws + WS_NW_OFF);
    int*   offs     = (int*)(ws + WS_OFFS_OFF);
    int*   fillpos  = (int*)(ws + WS_FILLPOS_OFF);
    int*   w_row    = (int*)(ws + WS_WROW_OFF);
    int*   w_lab    = (int*)(ws + WS_WLAB_OFF);
    int*   w_b      = (int*)(ws + WS_WB_OFF);
    int*   rowlist  = (int*)(ws + WS_ROWLIST_OFF);

    k0_zero<<<(ZERO_WORDS + 255) / 256, 256, 0, stream>>>((int*)(ws + WS_HIST_OFF));
    k1_kernel<<<K1_BLOCKS, 256, 0, stream>>>(inputs, features, cluster_mean,
                                             indexes, labels, targets,
                                             out_logits, out_feats, new_rows,
                                             hist, touched);
    k2_kernel<<<257, 256, 0, stream>>>(indexes, labels, new_rows, out_feats,
                                       hist, offs, fillpos, nw, w_row, w_lab, w_b);
    fill_kernel<<<(N + 255) / 256, 256, 0, stream>>>(labels, touched, fillpos, rowlist);
    cm_kernel<<<C, 1024, 0, stream>>>(cluster_mean, features, new_rows, touched,
                                      hist, offs, rowlist, nw, w_row, w_lab, w_b,
                                      out_cm);
}